// Round 1
// baseline (4770.104 us; speedup 1.0000x reference)
//
#include <hip/hip_runtime.h>
#include <float.h>

#define BNI 0.9999950000374997f  /* 1/sqrt(1+1e-5) */

__device__ __forceinline__ float sq3(float x, float y, float z) {
  // exact numpy semantics: (x*x + y*y) + z*z, no FMA contraction
  return __fadd_rn(__fadd_rn(__fmul_rn(x, x), __fmul_rn(y, y)), __fmul_rn(z, z));
}

// ---------------- prep: P4[i] = (x,y,z, x^2+y^2+z^2) ----------------
__global__ void k_prep(const float* __restrict__ p, float4* __restrict__ P4, int N) {
  int i = blockIdx.x * blockDim.x + threadIdx.x;
  if (i < N) {
    float x = p[3 * i], y = p[3 * i + 1], z = p[3 * i + 2];
    P4[i] = make_float4(x, y, z, sq3(x, y, z));
  }
}

// ---------------- enc1: X[pt,c] = relu(bn(cat(p0,x0) @ W1)) ----------------
__global__ __launch_bounds__(256) void k_enc1(
    const float* __restrict__ p0, const float* __restrict__ x0,
    const float* __restrict__ W, const float* __restrict__ g, const float* __restrict__ bt,
    float* __restrict__ X, int N) {
  int t = blockIdx.x * 256 + threadIdx.x;
  int pt = t >> 5, c = t & 31;
  if (pt >= N) return;
  float i0 = p0[pt * 3], i1 = p0[pt * 3 + 1], i2 = p0[pt * 3 + 2];
  float i3 = x0[pt * 3], i4 = x0[pt * 3 + 1], i5 = x0[pt * 3 + 2];
  float a = i0 * W[c] + i1 * W[32 + c] + i2 * W[64 + c] +
            i3 * W[96 + c] + i4 * W[128 + c] + i5 * W[160 + c];
  a = a * (g[c] * BNI) + bt[c];
  X[(size_t)pt * 32 + c] = fmaxf(a, 0.f);
}

// ---------------- FPS: one workgroup per batch, sequential furthest-point sampling ----------------
template <int PT>
__global__ void k_fps(const float4* __restrict__ P4, int n, int m, int* __restrict__ out_idx) {
  __shared__ float wlv[2][16];
  __shared__ int wli[2][16];
  const int b = blockIdx.x;
  const int T = blockDim.x;
  const int tid = threadIdx.x;
  const int lane = tid & 63, wid = tid >> 6;
  const int nw = T >> 6;
  const float4* P = P4 + (size_t)b * n;

  float px[PT], py[PT], pz[PT], dist[PT];
#pragma unroll
  for (int k = 0; k < PT; ++k) {
    int i = tid + k * T;
    float4 v = (i < n) ? P[i] : make_float4(0.f, 0.f, 0.f, 0.f);
    px[k] = v.x; py[k] = v.y; pz[k] = v.z;
    dist[k] = -1.f;
  }
  if (tid == 0) out_idx[(size_t)b * m] = 0;

  float4 q = P[0];
  float bv = -1.f;
  int bi = 0x7fffffff;
#pragma unroll
  for (int k = 0; k < PT; ++k) {
    int i = tid + k * T;
    if (i < n) {
      float dx = __fsub_rn(px[k], q.x), dy = __fsub_rn(py[k], q.y), dz = __fsub_rn(pz[k], q.z);
      dist[k] = sq3(dx, dy, dz);
      if (dist[k] > bv) { bv = dist[k]; bi = i; }  // slots ascending -> first-max kept
    }
  }

  for (int t = 1; t < m; ++t) {
    // wave argmax (tie -> lower index)
#pragma unroll
    for (int off = 1; off < 64; off <<= 1) {
      float ov = __shfl_xor(bv, off);
      int oi = __shfl_xor(bi, off);
      if (ov > bv || (ov == bv && oi < bi)) { bv = ov; bi = oi; }
    }
    int buf = t & 1;  // double-buffered partials -> single barrier per step
    if (lane == 0) { wlv[buf][wid] = bv; wli[buf][wid] = bi; }
    __syncthreads();
    float rv = (lane < nw) ? wlv[buf][lane] : -1.f;
    int ri = (lane < nw) ? wli[buf][lane] : 0x7fffffff;
#pragma unroll
    for (int off = 1; off < 16; off <<= 1) {
      float ov = __shfl_xor(rv, off);
      int oi = __shfl_xor(ri, off);
      if (ov > rv || (ov == rv && oi < ri)) { rv = ov; ri = oi; }
    }
    int wi = __shfl(ri, 0);
    if (tid == 0) out_idx[(size_t)b * m + t] = wi;
    if (t + 1 >= m) break;
    q = P[wi];  // broadcast load (same address all lanes, L1/L2 resident)
    bv = -1.f; bi = 0x7fffffff;
#pragma unroll
    for (int k = 0; k < PT; ++k) {
      float dx = __fsub_rn(px[k], q.x), dy = __fsub_rn(py[k], q.y), dz = __fsub_rn(pz[k], q.z);
      float d = sq3(dx, dy, dz);
      float nd = fminf(dist[k], d);  // invalid slots stay at -1
      dist[k] = nd;
      if (nd > bv) { bv = nd; bi = tid + k * T; }
    }
  }
}

// ---------------- gather sampled points (pp copied — bit-identical) ----------------
__global__ void k_gather(const float4* __restrict__ Pin, const int* __restrict__ idx,
                         float4* __restrict__ Pout, int n, int m, int total) {
  int t = blockIdx.x * blockDim.x + threadIdx.x;
  if (t >= total) return;
  int b = t / m;
  Pout[t] = Pin[(size_t)b * n + idx[t]];
}

// ---------------- KNN: one wave per query; exact expanded-form d2 ----------------
__global__ __launch_bounds__(256) void k_knn(
    const float4* __restrict__ Pq, const float4* __restrict__ Pc,
    int n, int m, int* __restrict__ knn) {
  int gw = (blockIdx.x * 256 + threadIdx.x) >> 6;
  int lane = threadIdx.x & 63;
  int b = gw / m;
  float4 q = Pq[gw];
  const float4* C = Pc + (size_t)b * n;
  float ad[8];
  int ai[8];
#pragma unroll
  for (int s = 0; s < 8; ++s) { ad[s] = FLT_MAX; ai[s] = 0x7fffffff; }
  for (int j = lane; j < n; j += 64) {
    float4 c = C[j];
    float dot = __fadd_rn(__fadd_rn(__fmul_rn(q.x, c.x), __fmul_rn(q.y, c.y)), __fmul_rn(q.z, c.z));
    float d2 = __fsub_rn(__fadd_rn(q.w, c.w), __fmul_rn(2.f, dot));  // (qq+pp) - 2*dot
    if (d2 < ad[7] || (d2 == ad[7] && j < ai[7])) {
      float cd = d2; int ci = j;
#pragma unroll
      for (int s = 0; s < 8; ++s) {
        bool sw = (cd < ad[s]) || (cd == ad[s] && ci < ai[s]);
        float td = ad[s]; int ti = ai[s];
        ad[s] = sw ? cd : td; ai[s] = sw ? ci : ti;
        cd = sw ? td : cd;  ci = sw ? ti : ci;
      }
    }
  }
  // merge 64 lanes' sorted top-8 -> global top-8 (8 rounds of wave-min)
  int pos = 0;
  int* kout = knn + (size_t)gw * 8;
#pragma unroll
  for (int r = 0; r < 8; ++r) {
    float hv = FLT_MAX; int hi = 0x7fffffff;
#pragma unroll
    for (int s = 7; s >= 0; --s)
      if (pos == s) { hv = ad[s]; hi = ai[s]; }
    float v = hv; int ix = hi;
#pragma unroll
    for (int off = 1; off < 64; off <<= 1) {
      float ov = __shfl_xor(v, off);
      int oi = __shfl_xor(ix, off);
      if (ov < v || (ov == v && oi < ix)) { v = ov; ix = oi; }
    }
    if (hv == v && hi == ix) pos++;  // unique owner (point indices unique)
    if (lane == 0) kout[r] = ix;
  }
}

// ---------------- grouped feature transform + BN/ReLU + maxpool over k=8 ----------------
template <int CINF, int COUT>
__global__ __launch_bounds__(COUT) void k_feat(
    const float4* __restrict__ Pq, const float4* __restrict__ Pc,
    const float* __restrict__ Xin, const int* __restrict__ knn,
    const float* __restrict__ W, const float* __restrict__ g, const float* __restrict__ bt,
    float* __restrict__ Xout, int n, int m) {
  constexpr int F = 3 + CINF;
  __shared__ float sf[8][F];
  int bi = blockIdx.x;  // = b*m + i
  int b = bi / m;
  int tid = threadIdx.x;
  float4 q = Pq[bi];
  const int* kn = knn + (size_t)bi * 8;
  if (tid < 8) {
    int nb = kn[tid];
    float4 c = Pc[(size_t)b * n + nb];
    sf[tid][0] = c.x - q.x;
    sf[tid][1] = c.y - q.y;
    sf[tid][2] = c.z - q.z;
  }
  for (int e = tid; e < 8 * CINF; e += COUT) {
    int k = e / CINF, j = e - k * CINF;
    int nb = kn[k];
    sf[k][3 + j] = Xin[((size_t)b * n + nb) * CINF + j];
  }
  __syncthreads();
  int c = tid;
  float acc[8] = {0.f, 0.f, 0.f, 0.f, 0.f, 0.f, 0.f, 0.f};
  for (int j = 0; j < F; ++j) {
    float w = W[(size_t)j * COUT + c];
#pragma unroll
    for (int k = 0; k < 8; ++k) acc[k] = fmaf(sf[k][j], w, acc[k]);
  }
  float sc = g[c] * BNI, bb = bt[c];
  float mx = 0.f;  // max_k relu(y_k) == max(0, max_k y_k)
#pragma unroll
  for (int k = 0; k < 8; ++k) mx = fmaxf(mx, fmaf(acc[k], sc, bb));
  Xout[(size_t)bi * COUT + c] = mx;
}

// ---------------- head: mean-pool + fc/bn/relu + fc ----------------
__global__ __launch_bounds__(512) void k_head(
    const float* __restrict__ X5, const float* __restrict__ Wc1, const float* __restrict__ bc1,
    const float* __restrict__ gc, const float* __restrict__ bcl,
    const float* __restrict__ Wc2, const float* __restrict__ bc2,
    float* __restrict__ out, int m5) {
  __shared__ float sp[512];
  __shared__ float sh[256];
  int b = blockIdx.x, tid = threadIdx.x;
  float s = 0.f;
  for (int i = 0; i < m5; ++i) s += X5[((size_t)b * m5 + i) * 512 + tid];
  sp[tid] = s * (1.0f / m5);
  __syncthreads();
  if (tid < 256) {
    float a = bc1[tid];
    for (int j = 0; j < 512; ++j) a = fmaf(sp[j], Wc1[j * 256 + tid], a);
    a = a * (gc[tid] * BNI) + bcl[tid];
    sh[tid] = fmaxf(a, 0.f);
  }
  __syncthreads();
  if (tid < 40) {
    float a = bc2[tid];
    for (int j = 0; j < 256; ++j) a = fmaf(sh[j], Wc2[j * 40 + tid], a);
    out[b * 40 + tid] = a;
  }
}

extern "C" void kernel_launch(void* const* d_in, const int* in_sizes, int n_in,
                              void* d_out, int out_size, void* d_ws, size_t ws_size,
                              hipStream_t stream) {
  const float* p0 = (const float*)d_in[0];
  const float* x0 = (const float*)d_in[1];
  const int B = in_sizes[2];
  const int N = in_sizes[0] / 3;
  const int n = N / B;  // 8192
  const float* W1 = (const float*)d_in[3];
  const float* g1 = (const float*)d_in[4];
  const float* b1 = (const float*)d_in[5];
  const float* W2 = (const float*)d_in[6];
  const float* g2 = (const float*)d_in[7];
  const float* b2 = (const float*)d_in[8];
  const float* W3 = (const float*)d_in[9];
  const float* g3 = (const float*)d_in[10];
  const float* b3 = (const float*)d_in[11];
  const float* W4 = (const float*)d_in[12];
  const float* g4 = (const float*)d_in[13];
  const float* b4 = (const float*)d_in[14];
  const float* W5 = (const float*)d_in[15];
  const float* g5 = (const float*)d_in[16];
  const float* b5 = (const float*)d_in[17];
  const float* Wc1 = (const float*)d_in[18];
  const float* bc1 = (const float*)d_in[19];
  const float* gcls = (const float*)d_in[20];
  const float* bcls = (const float*)d_in[21];
  const float* Wc2 = (const float*)d_in[22];
  const float* bc2 = (const float*)d_in[23];
  float* out = (float*)d_out;

  const int m2 = n / 4, m3 = m2 / 4, m4 = m3 / 4, m5 = m4 / 4;

  char* ws = (char*)d_ws;
  size_t off = 0;
  auto alloc = [&](size_t bytes) -> void* {
    void* p = ws + off;
    off += (bytes + 255) & ~(size_t)255;
    return p;
  };
  float4* P2 = (float4*)alloc((size_t)N * 16);
  float* X1 = (float*)alloc((size_t)N * 32 * 4);
  float4* P3 = (float4*)alloc((size_t)B * m2 * 16);
  float4* P4s = (float4*)alloc((size_t)B * m3 * 16);
  float4* P5 = (float4*)alloc((size_t)B * m4 * 16);
  float4* P6 = (float4*)alloc((size_t)B * m5 * 16);
  int* fpsI = (int*)alloc((size_t)B * m2 * 4);
  int* knnI = (int*)alloc((size_t)B * m2 * 8 * 4);
  float* X2 = (float*)alloc((size_t)B * m2 * 64 * 4);
  float* X3 = (float*)alloc((size_t)B * m3 * 128 * 4);
  float* X4 = (float*)alloc((size_t)B * m4 * 256 * 4);
  float* X5 = (float*)alloc((size_t)B * m5 * 512 * 4);

  k_prep<<<(N + 255) / 256, 256, 0, stream>>>(p0, P2, N);
  k_enc1<<<(N * 32 + 255) / 256, 256, 0, stream>>>(p0, x0, W1, g1, b1, X1, N);

  // stage 2: n=8192 -> m=2048, feat 3+32 -> 64
  k_fps<8><<<B, 1024, 0, stream>>>(P2, n, m2, fpsI);
  k_gather<<<(B * m2 + 255) / 256, 256, 0, stream>>>(P2, fpsI, P3, n, m2, B * m2);
  k_knn<<<(B * m2) / 4, 256, 0, stream>>>(P3, P2, n, m2, knnI);
  k_feat<32, 64><<<B * m2, 64, 0, stream>>>(P3, P2, X1, knnI, W2, g2, b2, X2, n, m2);

  // stage 3: 2048 -> 512, 3+64 -> 128
  k_fps<4><<<B, 512, 0, stream>>>(P3, m2, m3, fpsI);
  k_gather<<<(B * m3 + 255) / 256, 256, 0, stream>>>(P3, fpsI, P4s, m2, m3, B * m3);
  k_knn<<<(B * m3) / 4, 256, 0, stream>>>(P4s, P3, m2, m3, knnI);
  k_feat<64, 128><<<B * m3, 128, 0, stream>>>(P4s, P3, X2, knnI, W3, g3, b3, X3, m2, m3);

  // stage 4: 512 -> 128, 3+128 -> 256
  k_fps<2><<<B, 256, 0, stream>>>(P4s, m3, m4, fpsI);
  k_gather<<<(B * m4 + 255) / 256, 256, 0, stream>>>(P4s, fpsI, P5, m3, m4, B * m4);
  k_knn<<<(B * m4) / 4, 256, 0, stream>>>(P5, P4s, m3, m4, knnI);
  k_feat<128, 256><<<B * m4, 256, 0, stream>>>(P5, P4s, X3, knnI, W4, g4, b4, X4, m3, m4);

  // stage 5: 128 -> 32, 3+256 -> 512
  k_fps<1><<<B, 128, 0, stream>>>(P5, m4, m5, fpsI);
  k_gather<<<(B * m5 + 255) / 256, 256, 0, stream>>>(P5, fpsI, P6, m4, m5, B * m5);
  k_knn<<<(B * m5) / 4, 256, 0, stream>>>(P6, P5, m4, m5, knnI);
  k_feat<256, 512><<<B * m5, 512, 0, stream>>>(P6, P5, X4, knnI, W5, g5, b5, X5, m4, m5);

  // head
  k_head<<<B, 512, 0, stream>>>(X5, Wc1, bc1, gcls, bcls, Wc2, bc2, out, m5);
}

// Round 2
// 2995.030 us; speedup vs baseline: 1.5927x; 1.5927x over previous
//
#include <hip/hip_runtime.h>
#include <float.h>

#define BNI 0.9999950000374997f  /* 1/sqrt(1+1e-5) */

__device__ __forceinline__ float sq3(float x, float y, float z) {
  // exact numpy semantics: (x*x + y*y) + z*z, no FMA contraction
  return __fadd_rn(__fadd_rn(__fmul_rn(x, x), __fmul_rn(y, y)), __fmul_rn(z, z));
}

// ---- packed argmax key: (float_bits(v) << 32) | ~idx, as positive f64 ----
// v >= 0 always  ->  key is a positive double; f64 max ordering == u64 ordering.
// Ties in v resolve to larger ~idx == smaller idx (numpy first-max semantics).
__device__ __forceinline__ double pack_key(float v, int idx) {
  unsigned long long u =
      ((unsigned long long)__float_as_uint(v) << 32) | (unsigned int)(~idx);
  return __longlong_as_double((long long)u);
}
__device__ __forceinline__ int key_idx(double k) {
  return ~(int)(unsigned int)(unsigned long long)__double_as_longlong(k);
}

// one butterfly level via DPP (VALU-latency cross-lane, no DS round-trip)
template <int CTRL>
__device__ __forceinline__ double dpp_max(double k) {
  union { double d; int i[2]; } u, r;
  u.d = k;
  r.i[0] = __builtin_amdgcn_mov_dpp(u.i[0], CTRL, 0xF, 0xF, true);
  r.i[1] = __builtin_amdgcn_mov_dpp(u.i[1], CTRL, 0xF, 0xF, true);
  return fmax(k, r.d);
}
// lane ^ 16 (within 32-lane halves)
__device__ __forceinline__ double swz16_max(double k) {
  union { double d; int i[2]; } u, r;
  u.d = k;
  r.i[0] = __builtin_amdgcn_ds_swizzle(u.i[0], 0x401F);
  r.i[1] = __builtin_amdgcn_ds_swizzle(u.i[1], 0x401F);
  return fmax(k, r.d);
}
// lane ^ 32 (full-wave)
__device__ __forceinline__ double bperm32_max(double k, int lane) {
  union { double d; int i[2]; } u, r;
  u.d = k;
  int addr = ((lane ^ 32) << 2);
  r.i[0] = __builtin_amdgcn_ds_bpermute(addr, u.i[0]);
  r.i[1] = __builtin_amdgcn_ds_bpermute(addr, u.i[1]);
  return fmax(k, r.d);
}
// full 64-lane max: 4 DPP levels + 2 DS-class levels; result in ALL lanes
__device__ __forceinline__ double wave_max(double k, int lane) {
  k = dpp_max<0xB1>(k);    // quad_perm [1,0,3,2]  : xor 1
  k = dpp_max<0x4E>(k);    // quad_perm [2,3,0,1]  : xor 2
  k = dpp_max<0x141>(k);   // row_half_mirror      : joins 4-groups -> 8
  k = dpp_max<0x140>(k);   // row_mirror (^15)     : joins 8-groups -> 16
  k = swz16_max(k);        // xor 16
  k = bperm32_max(k, lane);// xor 32
  return k;
}

// ---------------- prep: P4[i] = (x,y,z, x^2+y^2+z^2) ----------------
__global__ void k_prep(const float* __restrict__ p, float4* __restrict__ P4, int N) {
  int i = blockIdx.x * blockDim.x + threadIdx.x;
  if (i < N) {
    float x = p[3 * i], y = p[3 * i + 1], z = p[3 * i + 2];
    P4[i] = make_float4(x, y, z, sq3(x, y, z));
  }
}

// ---------------- enc1: X[pt,c] = relu(bn(cat(p0,x0) @ W1)) ----------------
__global__ __launch_bounds__(256) void k_enc1(
    const float* __restrict__ p0, const float* __restrict__ x0,
    const float* __restrict__ W, const float* __restrict__ g, const float* __restrict__ bt,
    float* __restrict__ X, int N) {
  int t = blockIdx.x * 256 + threadIdx.x;
  int pt = t >> 5, c = t & 31;
  if (pt >= N) return;
  float i0 = p0[pt * 3], i1 = p0[pt * 3 + 1], i2 = p0[pt * 3 + 2];
  float i3 = x0[pt * 3], i4 = x0[pt * 3 + 1], i5 = x0[pt * 3 + 2];
  float a = i0 * W[c] + i1 * W[32 + c] + i2 * W[64 + c] +
            i3 * W[96 + c] + i4 * W[128 + c] + i5 * W[160 + c];
  a = a * (g[c] * BNI) + bt[c];
  X[(size_t)pt * 32 + c] = fmaxf(a, 0.f);
}

// ---------------- FPS: one workgroup per batch; DPP packed-key argmax ----------------
// T = 64*NW threads, PT points per thread, PT*T == n exactly for all stages.
template <int PT, int NW>
__global__ __launch_bounds__(64 * NW) void k_fps(
    const float4* __restrict__ P4, int n, int m, int* __restrict__ out_idx) {
  __shared__ double keys[2][16];
  const int b = blockIdx.x;
  const int T = 64 * NW;
  const int tid = threadIdx.x;
  const int lane = tid & 63, wid = tid >> 6;
  const float4* P = P4 + (size_t)b * n;

  float px[PT], py[PT], pz[PT], dist[PT];
#pragma unroll
  for (int k = 0; k < PT; ++k) {
    int i = tid + k * T;
    float4 v = P[i];
    px[k] = v.x; py[k] = v.y; pz[k] = v.z;
  }
  if (tid == 0) out_idx[(size_t)b * m] = 0;

  float4 q = P[0];
  float bv = -1.f;
  int bi = 0x7fffffff;
#pragma unroll
  for (int k = 0; k < PT; ++k) {
    float dx = __fsub_rn(px[k], q.x), dy = __fsub_rn(py[k], q.y), dz = __fsub_rn(pz[k], q.z);
    dist[k] = sq3(dx, dy, dz);
    if (dist[k] > bv) { bv = dist[k]; bi = tid + k * T; }  // k ascending -> first-max kept
  }
  double key = pack_key(bv, bi);

  for (int t = 1; t < m; ++t) {
    key = wave_max(key, lane);
    int buf = t & 1;  // double-buffered wave partials -> single barrier per step
    if (lane == 0) keys[buf][wid] = key;
    __syncthreads();
    double kb = keys[buf][lane & (NW - 1)];  // replicated read; broadcast, conflict-free
    if (NW >= 2)  kb = dpp_max<0xB1>(kb);
    if (NW >= 4)  kb = dpp_max<0x4E>(kb);
    if (NW >= 8)  kb = dpp_max<0x141>(kb);
    if (NW >= 16) kb = dpp_max<0x140>(kb);
    int wi = key_idx(kb);
    if (tid == 0) out_idx[(size_t)b * m + t] = wi;
    if (t + 1 >= m) break;
    q = P[wi];  // uniform-address load, L2 resident
    bv = -1.f; bi = 0x7fffffff;
#pragma unroll
    for (int k = 0; k < PT; ++k) {
      float dx = __fsub_rn(px[k], q.x), dy = __fsub_rn(py[k], q.y), dz = __fsub_rn(pz[k], q.z);
      float d = sq3(dx, dy, dz);
      float nd = fminf(dist[k], d);
      dist[k] = nd;
      if (nd > bv) { bv = nd; bi = tid + k * T; }
    }
    key = pack_key(bv, bi);
  }
}

// ---------------- gather sampled points (pp copied — bit-identical) ----------------
__global__ void k_gather(const float4* __restrict__ Pin, const int* __restrict__ idx,
                         float4* __restrict__ Pout, int n, int m, int total) {
  int t = blockIdx.x * blockDim.x + threadIdx.x;
  if (t >= total) return;
  int b = t / m;
  Pout[t] = Pin[(size_t)b * n + idx[t]];
}

// ---------------- KNN: one wave per query; exact expanded-form d2 ----------------
__global__ __launch_bounds__(256) void k_knn(
    const float4* __restrict__ Pq, const float4* __restrict__ Pc,
    int n, int m, int* __restrict__ knn) {
  int gw = (blockIdx.x * 256 + threadIdx.x) >> 6;
  int lane = threadIdx.x & 63;
  int b = gw / m;
  float4 q = Pq[gw];
  const float4* C = Pc + (size_t)b * n;
  float ad[8];
  int ai[8];
#pragma unroll
  for (int s = 0; s < 8; ++s) { ad[s] = FLT_MAX; ai[s] = 0x7fffffff; }
  for (int j = lane; j < n; j += 64) {
    float4 c = C[j];
    float dot = __fadd_rn(__fadd_rn(__fmul_rn(q.x, c.x), __fmul_rn(q.y, c.y)), __fmul_rn(q.z, c.z));
    float d2 = __fsub_rn(__fadd_rn(q.w, c.w), __fmul_rn(2.f, dot));  // (qq+pp) - 2*dot
    if (d2 < ad[7] || (d2 == ad[7] && j < ai[7])) {
      float cd = d2; int ci = j;
#pragma unroll
      for (int s = 0; s < 8; ++s) {
        bool sw = (cd < ad[s]) || (cd == ad[s] && ci < ai[s]);
        float td = ad[s]; int ti = ai[s];
        ad[s] = sw ? cd : td; ai[s] = sw ? ci : ti;
        cd = sw ? td : cd;  ci = sw ? ti : ci;
      }
    }
  }
  // merge 64 lanes' sorted top-8 -> global top-8 (8 rounds of wave-min)
  int pos = 0;
  int* kout = knn + (size_t)gw * 8;
#pragma unroll
  for (int r = 0; r < 8; ++r) {
    float hv = FLT_MAX; int hi = 0x7fffffff;
#pragma unroll
    for (int s = 7; s >= 0; --s)
      if (pos == s) { hv = ad[s]; hi = ai[s]; }
    float v = hv; int ix = hi;
#pragma unroll
    for (int off = 1; off < 64; off <<= 1) {
      float ov = __shfl_xor(v, off);
      int oi = __shfl_xor(ix, off);
      if (ov < v || (ov == v && oi < ix)) { v = ov; ix = oi; }
    }
    if (hv == v && hi == ix) pos++;  // unique owner (point indices unique)
    if (lane == 0) kout[r] = ix;
  }
}

// ---------------- grouped feature transform + BN/ReLU + maxpool over k=8 ----------------
template <int CINF, int COUT>
__global__ __launch_bounds__(COUT) void k_feat(
    const float4* __restrict__ Pq, const float4* __restrict__ Pc,
    const float* __restrict__ Xin, const int* __restrict__ knn,
    const float* __restrict__ W, const float* __restrict__ g, const float* __restrict__ bt,
    float* __restrict__ Xout, int n, int m) {
  constexpr int F = 3 + CINF;
  __shared__ float sf[8][F];
  int bi = blockIdx.x;  // = b*m + i
  int b = bi / m;
  int tid = threadIdx.x;
  float4 q = Pq[bi];
  const int* kn = knn + (size_t)bi * 8;
  if (tid < 8) {
    int nb = kn[tid];
    float4 c = Pc[(size_t)b * n + nb];
    sf[tid][0] = c.x - q.x;
    sf[tid][1] = c.y - q.y;
    sf[tid][2] = c.z - q.z;
  }
  for (int e = tid; e < 8 * CINF; e += COUT) {
    int k = e / CINF, j = e - k * CINF;
    int nb = kn[k];
    sf[k][3 + j] = Xin[((size_t)b * n + nb) * CINF + j];
  }
  __syncthreads();
  int c = tid;
  float acc[8] = {0.f, 0.f, 0.f, 0.f, 0.f, 0.f, 0.f, 0.f};
  for (int j = 0; j < F; ++j) {
    float w = W[(size_t)j * COUT + c];
#pragma unroll
    for (int k = 0; k < 8; ++k) acc[k] = fmaf(sf[k][j], w, acc[k]);
  }
  float sc = g[c] * BNI, bb = bt[c];
  float mx = 0.f;  // max_k relu(y_k) == max(0, max_k y_k)
#pragma unroll
  for (int k = 0; k < 8; ++k) mx = fmaxf(mx, fmaf(acc[k], sc, bb));
  Xout[(size_t)bi * COUT + c] = mx;
}

// ---------------- head: mean-pool + fc/bn/relu + fc ----------------
__global__ __launch_bounds__(512) void k_head(
    const float* __restrict__ X5, const float* __restrict__ Wc1, const float* __restrict__ bc1,
    const float* __restrict__ gc, const float* __restrict__ bcl,
    const float* __restrict__ Wc2, const float* __restrict__ bc2,
    float* __restrict__ out, int m5) {
  __shared__ float sp[512];
  __shared__ float sh[256];
  int b = blockIdx.x, tid = threadIdx.x;
  float s = 0.f;
  for (int i = 0; i < m5; ++i) s += X5[((size_t)b * m5 + i) * 512 + tid];
  sp[tid] = s * (1.0f / m5);
  __syncthreads();
  if (tid < 256) {
    float a = bc1[tid];
    for (int j = 0; j < 512; ++j) a = fmaf(sp[j], Wc1[j * 256 + tid], a);
    a = a * (gc[tid] * BNI) + bcl[tid];
    sh[tid] = fmaxf(a, 0.f);
  }
  __syncthreads();
  if (tid < 40) {
    float a = bc2[tid];
    for (int j = 0; j < 256; ++j) a = fmaf(sh[j], Wc2[j * 40 + tid], a);
    out[b * 40 + tid] = a;
  }
}

extern "C" void kernel_launch(void* const* d_in, const int* in_sizes, int n_in,
                              void* d_out, int out_size, void* d_ws, size_t ws_size,
                              hipStream_t stream) {
  const float* p0 = (const float*)d_in[0];
  const float* x0 = (const float*)d_in[1];
  const int B = in_sizes[2];
  const int N = in_sizes[0] / 3;
  const int n = N / B;  // 8192
  const float* W1 = (const float*)d_in[3];
  const float* g1 = (const float*)d_in[4];
  const float* b1 = (const float*)d_in[5];
  const float* W2 = (const float*)d_in[6];
  const float* g2 = (const float*)d_in[7];
  const float* b2 = (const float*)d_in[8];
  const float* W3 = (const float*)d_in[9];
  const float* g3 = (const float*)d_in[10];
  const float* b3 = (const float*)d_in[11];
  const float* W4 = (const float*)d_in[12];
  const float* g4 = (const float*)d_in[13];
  const float* b4 = (const float*)d_in[14];
  const float* W5 = (const float*)d_in[15];
  const float* g5 = (const float*)d_in[16];
  const float* b5 = (const float*)d_in[17];
  const float* Wc1 = (const float*)d_in[18];
  const float* bc1 = (const float*)d_in[19];
  const float* gcls = (const float*)d_in[20];
  const float* bcls = (const float*)d_in[21];
  const float* Wc2 = (const float*)d_in[22];
  const float* bc2 = (const float*)d_in[23];
  float* out = (float*)d_out;

  const int m2 = n / 4, m3 = m2 / 4, m4 = m3 / 4, m5 = m4 / 4;

  char* ws = (char*)d_ws;
  size_t off = 0;
  auto alloc = [&](size_t bytes) -> void* {
    void* p = ws + off;
    off += (bytes + 255) & ~(size_t)255;
    return p;
  };
  float4* P2 = (float4*)alloc((size_t)N * 16);
  float* X1 = (float*)alloc((size_t)N * 32 * 4);
  float4* P3 = (float4*)alloc((size_t)B * m2 * 16);
  float4* P4s = (float4*)alloc((size_t)B * m3 * 16);
  float4* P5 = (float4*)alloc((size_t)B * m4 * 16);
  float4* P6 = (float4*)alloc((size_t)B * m5 * 16);
  int* fpsI = (int*)alloc((size_t)B * m2 * 4);
  int* knnI = (int*)alloc((size_t)B * m2 * 8 * 4);
  float* X2 = (float*)alloc((size_t)B * m2 * 64 * 4);
  float* X3 = (float*)alloc((size_t)B * m3 * 128 * 4);
  float* X4 = (float*)alloc((size_t)B * m4 * 256 * 4);
  float* X5 = (float*)alloc((size_t)B * m5 * 512 * 4);

  k_prep<<<(N + 255) / 256, 256, 0, stream>>>(p0, P2, N);
  k_enc1<<<(N * 32 + 255) / 256, 256, 0, stream>>>(p0, x0, W1, g1, b1, X1, N);

  // stage 2: n=8192 -> m=2048, feat 3+32 -> 64
  k_fps<8, 16><<<B, 1024, 0, stream>>>(P2, n, m2, fpsI);
  k_gather<<<(B * m2 + 255) / 256, 256, 0, stream>>>(P2, fpsI, P3, n, m2, B * m2);
  k_knn<<<(B * m2) / 4, 256, 0, stream>>>(P3, P2, n, m2, knnI);
  k_feat<32, 64><<<B * m2, 64, 0, stream>>>(P3, P2, X1, knnI, W2, g2, b2, X2, n, m2);

  // stage 3: 2048 -> 512, 3+64 -> 128
  k_fps<4, 8><<<B, 512, 0, stream>>>(P3, m2, m3, fpsI);
  k_gather<<<(B * m3 + 255) / 256, 256, 0, stream>>>(P3, fpsI, P4s, m2, m3, B * m3);
  k_knn<<<(B * m3) / 4, 256, 0, stream>>>(P4s, P3, m2, m3, knnI);
  k_feat<64, 128><<<B * m3, 128, 0, stream>>>(P4s, P3, X2, knnI, W3, g3, b3, X3, m2, m3);

  // stage 4: 512 -> 128, 3+128 -> 256
  k_fps<2, 4><<<B, 256, 0, stream>>>(P4s, m3, m4, fpsI);
  k_gather<<<(B * m4 + 255) / 256, 256, 0, stream>>>(P4s, fpsI, P5, m3, m4, B * m4);
  k_knn<<<(B * m4) / 4, 256, 0, stream>>>(P5, P4s, m3, m4, knnI);
  k_feat<128, 256><<<B * m4, 256, 0, stream>>>(P5, P4s, X3, knnI, W4, g4, b4, X4, m3, m4);

  // stage 5: 128 -> 32, 3+256 -> 512
  k_fps<1, 2><<<B, 128, 0, stream>>>(P5, m4, m5, fpsI);
  k_gather<<<(B * m5 + 255) / 256, 256, 0, stream>>>(P5, fpsI, P6, m4, m5, B * m5);
  k_knn<<<(B * m5) / 4, 256, 0, stream>>>(P6, P5, m4, m5, knnI);
  k_feat<256, 512><<<B * m5, 512, 0, stream>>>(P6, P5, X4, knnI, W5, g5, b5, X5, m4, m5);

  // head
  k_head<<<B, 512, 0, stream>>>(X5, Wc1, bc1, gcls, bcls, Wc2, bc2, out, m5);
}

// Round 3
// 2621.378 us; speedup vs baseline: 1.8197x; 1.1425x over previous
//
#include <hip/hip_runtime.h>
#include <float.h>

#define BNI 0.9999950000374997f  /* 1/sqrt(1+1e-5) */

__device__ __forceinline__ float sq3(float x, float y, float z) {
  // exact numpy semantics: (x*x + y*y) + z*z, no FMA contraction
  return __fadd_rn(__fadd_rn(__fmul_rn(x, x), __fmul_rn(y, y)), __fmul_rn(z, z));
}

// ---- packed argmax key: (float_bits(v) << 32) | ~idx, as positive f64 ----
// v >= 0 -> key positive double; f64 max ordering == u64 ordering.
// Ties in v resolve to larger ~idx == smaller idx (numpy first-max semantics).
__device__ __forceinline__ int key_idx(double k) {
  return ~__double2loint(k);
}

// one butterfly level via DPP (VALU-latency cross-lane, no DS round-trip)
template <int CTRL>
__device__ __forceinline__ double dpp_max(double k) {
  union { double d; int i[2]; } u, r;
  u.d = k;
  r.i[0] = __builtin_amdgcn_mov_dpp(u.i[0], CTRL, 0xF, 0xF, true);
  r.i[1] = __builtin_amdgcn_mov_dpp(u.i[1], CTRL, 0xF, 0xF, true);
  return fmax(k, r.d);
}
__device__ __forceinline__ double swz16_max(double k) {  // lane ^ 16
  union { double d; int i[2]; } u, r;
  u.d = k;
  r.i[0] = __builtin_amdgcn_ds_swizzle(u.i[0], 0x401F);
  r.i[1] = __builtin_amdgcn_ds_swizzle(u.i[1], 0x401F);
  return fmax(k, r.d);
}
__device__ __forceinline__ double bperm32_max(double k, int lane) {  // lane ^ 32
  union { double d; int i[2]; } u, r;
  u.d = k;
  int addr = ((lane ^ 32) << 2);
  r.i[0] = __builtin_amdgcn_ds_bpermute(addr, u.i[0]);
  r.i[1] = __builtin_amdgcn_ds_bpermute(addr, u.i[1]);
  return fmax(k, r.d);
}
__device__ __forceinline__ double wave_max_key(double k, int lane) {
  k = dpp_max<0xB1>(k);     // xor 1
  k = dpp_max<0x4E>(k);     // xor 2
  k = dpp_max<0x141>(k);    // row_half_mirror : joins 4-groups -> 8
  k = dpp_max<0x140>(k);    // row_mirror      : joins 8-groups -> 16
  k = swz16_max(k);         // xor 16
  k = bperm32_max(k, lane); // xor 32
  return k;
}

// ---------------- prep: P4[i] = (x,y,z, x^2+y^2+z^2) ----------------
__global__ void k_prep(const float* __restrict__ p, float4* __restrict__ P4, int N) {
  int i = blockIdx.x * blockDim.x + threadIdx.x;
  if (i < N) {
    float x = p[3 * i], y = p[3 * i + 1], z = p[3 * i + 2];
    P4[i] = make_float4(x, y, z, sq3(x, y, z));
  }
}

// ---------------- enc1: X[pt,c] = relu(bn(cat(p0,x0) @ W1)) ----------------
__global__ __launch_bounds__(256) void k_enc1(
    const float* __restrict__ p0, const float* __restrict__ x0,
    const float* __restrict__ W, const float* __restrict__ g, const float* __restrict__ bt,
    float* __restrict__ X, int N) {
  int t = blockIdx.x * 256 + threadIdx.x;
  int pt = t >> 5, c = t & 31;
  if (pt >= N) return;
  float i0 = p0[pt * 3], i1 = p0[pt * 3 + 1], i2 = p0[pt * 3 + 2];
  float i3 = x0[pt * 3], i4 = x0[pt * 3 + 1], i5 = x0[pt * 3 + 2];
  float a = i0 * W[c] + i1 * W[32 + c] + i2 * W[64 + c] +
            i3 * W[96 + c] + i4 * W[128 + c] + i5 * W[160 + c];
  a = a * (g[c] * BNI) + bt[c];
  X[(size_t)pt * 32 + c] = fmaxf(a, 0.f);
}

// ================= spatial sort (Morton 8^3 counting sort) =================
__device__ __forceinline__ unsigned mpart3(unsigned x) {  // 3 bits -> bits 0,3,6
  return (x & 1u) | ((x & 2u) << 2) | ((x & 4u) << 4);
}
__device__ __forceinline__ int cell_id(float4 v, const float* __restrict__ bb) {
  int cx = min(max((int)((v.x - bb[0]) * bb[3]), 0), 7);
  int cy = min(max((int)((v.y - bb[1]) * bb[4]), 0), 7);
  int cz = min(max((int)((v.z - bb[2]) * bb[5]), 0), 7);
  return (int)((mpart3(cx) << 2) | (mpart3(cy) << 1) | mpart3(cz));
}

__global__ __launch_bounds__(256) void k_bbox(const float4* __restrict__ P, int n,
                                              float* __restrict__ bb) {
  __shared__ float sm[6][4];
  int b = blockIdx.x, tid = threadIdx.x, lane = tid & 63, wid = tid >> 6;
  const float4* Pb = P + (size_t)b * n;
  float lx = FLT_MAX, hx = -FLT_MAX, ly = FLT_MAX, hy = -FLT_MAX, lz = FLT_MAX, hz = -FLT_MAX;
  for (int i = tid; i < n; i += 256) {
    float4 v = Pb[i];
    lx = fminf(lx, v.x); hx = fmaxf(hx, v.x);
    ly = fminf(ly, v.y); hy = fmaxf(hy, v.y);
    lz = fminf(lz, v.z); hz = fmaxf(hz, v.z);
  }
#pragma unroll
  for (int off = 1; off < 64; off <<= 1) {
    lx = fminf(lx, __shfl_xor(lx, off)); hx = fmaxf(hx, __shfl_xor(hx, off));
    ly = fminf(ly, __shfl_xor(ly, off)); hy = fmaxf(hy, __shfl_xor(hy, off));
    lz = fminf(lz, __shfl_xor(lz, off)); hz = fmaxf(hz, __shfl_xor(hz, off));
  }
  if (lane == 0) {
    sm[0][wid] = lx; sm[1][wid] = hx; sm[2][wid] = ly;
    sm[3][wid] = hy; sm[4][wid] = lz; sm[5][wid] = hz;
  }
  __syncthreads();
  if (tid == 0) {
    float LX = fminf(fminf(sm[0][0], sm[0][1]), fminf(sm[0][2], sm[0][3]));
    float HX = fmaxf(fmaxf(sm[1][0], sm[1][1]), fmaxf(sm[1][2], sm[1][3]));
    float LY = fminf(fminf(sm[2][0], sm[2][1]), fminf(sm[2][2], sm[2][3]));
    float HY = fmaxf(fmaxf(sm[3][0], sm[3][1]), fmaxf(sm[3][2], sm[3][3]));
    float LZ = fminf(fminf(sm[4][0], sm[4][1]), fminf(sm[4][2], sm[4][3]));
    float HZ = fmaxf(fmaxf(sm[5][0], sm[5][1]), fmaxf(sm[5][2], sm[5][3]));
    float ex = HX - LX, ey = HY - LY, ez = HZ - LZ;
    float* o = bb + b * 8;
    o[0] = LX; o[1] = LY; o[2] = LZ;
    o[3] = ex > 0.f ? 8.f / ex : 0.f;
    o[4] = ey > 0.f ? 8.f / ey : 0.f;
    o[5] = ez > 0.f ? 8.f / ez : 0.f;
  }
}

__global__ void k_hist(const float4* __restrict__ P, const float* __restrict__ bb,
                       int* __restrict__ hist, int n, int total) {
  int i = blockIdx.x * blockDim.x + threadIdx.x;
  if (i >= total) return;
  int b = i / n;
  int cid = cell_id(P[i], bb + b * 8);
  atomicAdd(&hist[b * 512 + cid], 1);
}

__global__ __launch_bounds__(512) void k_scan(const int* __restrict__ hist,
                                              int* __restrict__ cursor) {
  __shared__ int s[512];
  int b = blockIdx.x, t = threadIdx.x;
  int h = hist[b * 512 + t];
  s[t] = h;
  __syncthreads();
  for (int d = 1; d < 512; d <<= 1) {
    int v = (t >= d) ? s[t - d] : 0;
    __syncthreads();
    s[t] += v;
    __syncthreads();
  }
  cursor[b * 512 + t] = s[t] - h;  // exclusive
}

__global__ void k_scatter(const float4* __restrict__ P, const float* __restrict__ bb,
                          int* __restrict__ cursor, float4* __restrict__ Psort,
                          int n, int total) {
  int i = blockIdx.x * blockDim.x + threadIdx.x;
  if (i >= total) return;
  int b = i / n, il = i - b * n;
  float4 v = P[i];
  int cid = cell_id(v, bb + b * 8);
  int pos = atomicAdd(&cursor[b * 512 + cid], 1);
  Psort[(size_t)b * n + pos] = make_float4(v.x, v.y, v.z, __int_as_float(il));
}

// ---------------- FPS with exact wave-level bbox pruning ----------------
// Wave w owns sorted points [w*64*PT, (w+1)*64*PT); lane slot k = base + k*64 + lane.
// Skip update when lower-bound d2(bbox, q) >= wave max dist: mathematically a no-op
// (monotone rn arithmetic -> lb <= true d2 per point), so dist AND wave key unchanged.
template <int PT, int NW>
__global__ __launch_bounds__(64 * NW) void k_fps(
    const float4* __restrict__ Psort, const float4* __restrict__ Porig,
    int n, int m, int* __restrict__ out_idx) {
  __shared__ double keys[2][NW];
  const int b = blockIdx.x;
  const int tid = threadIdx.x;
  const int lane = tid & 63, wid = tid >> 6;
  const float4* PS = Psort + (size_t)b * n;
  const float4* PO = Porig + (size_t)b * n;

  float px[PT], py[PT], pz[PT], dist[PT];
  int ni[PT];  // ~orig_idx (constant per slot)
  const int base = wid * (64 * PT);
#pragma unroll
  for (int k = 0; k < PT; ++k) {
    float4 v = PS[base + k * 64 + lane];
    px[k] = v.x; py[k] = v.y; pz[k] = v.z;
    ni[k] = ~__float_as_int(v.w);
  }
  // wave bbox (one-time)
  float lx = px[0], hx = px[0], ly = py[0], hy = py[0], lz = pz[0], hz = pz[0];
#pragma unroll
  for (int k = 1; k < PT; ++k) {
    lx = fminf(lx, px[k]); hx = fmaxf(hx, px[k]);
    ly = fminf(ly, py[k]); hy = fmaxf(hy, py[k]);
    lz = fminf(lz, pz[k]); hz = fmaxf(hz, pz[k]);
  }
#pragma unroll
  for (int off = 1; off < 64; off <<= 1) {
    lx = fminf(lx, __shfl_xor(lx, off)); hx = fmaxf(hx, __shfl_xor(hx, off));
    ly = fminf(ly, __shfl_xor(ly, off)); hy = fmaxf(hy, __shfl_xor(hy, off));
    lz = fminf(lz, __shfl_xor(lz, off)); hz = fmaxf(hz, __shfl_xor(hz, off));
  }
  if (tid == 0) out_idx[(size_t)b * m] = 0;

  float4 q = PO[0];
  double lk = -1.0;
#pragma unroll
  for (int k = 0; k < PT; ++k) {
    float dx = __fsub_rn(px[k], q.x), dy = __fsub_rn(py[k], q.y), dz = __fsub_rn(pz[k], q.z);
    float d = sq3(dx, dy, dz);
    dist[k] = d;
    lk = fmax(lk, __hiloint2double(__float_as_int(d), ni[k]));
  }
  double wkey = wave_max_key(lk, lane);

  for (int t = 1; t < m; ++t) {
    int buf = t & 1;  // double-buffered wave partials -> single barrier per step
    if (lane == 0) keys[buf][wid] = wkey;
    __syncthreads();
    double kb = keys[buf][lane & (NW - 1)];  // replicated broadcast read
    if (NW >= 2)  kb = dpp_max<0xB1>(kb);
    if (NW >= 4)  kb = dpp_max<0x4E>(kb);
    if (NW >= 8)  kb = dpp_max<0x141>(kb);
    if (NW >= 16) kb = dpp_max<0x140>(kb);
    int wi = key_idx(kb);
    if (tid == 0) out_idx[(size_t)b * m + t] = wi;
    if (t + 1 >= m) break;
    float4 qq = PO[wi];  // uniform-address load, L2 resident
    // exact lower bound of d2 from this wave's points to qq (monotone rn ops)
    float tx = fmaxf(fmaxf(__fsub_rn(lx, qq.x), __fsub_rn(qq.x, hx)), 0.f);
    float ty = fmaxf(fmaxf(__fsub_rn(ly, qq.y), __fsub_rn(qq.y, hy)), 0.f);
    float tz = fmaxf(fmaxf(__fsub_rn(lz, qq.z), __fsub_rn(qq.z, hz)), 0.f);
    float lb = sq3(tx, ty, tz);
    float wv = __uint_as_float((unsigned)__double2hiint(wkey));
    if (lb < wv) {  // wave-uniform branch; prune == provable no-op
      double lk2 = -1.0;
#pragma unroll
      for (int k = 0; k < PT; ++k) {
        float dx = __fsub_rn(px[k], qq.x), dy = __fsub_rn(py[k], qq.y), dz = __fsub_rn(pz[k], qq.z);
        float d = sq3(dx, dy, dz);
        float nd = fminf(dist[k], d);
        dist[k] = nd;
        lk2 = fmax(lk2, __hiloint2double(__float_as_int(nd), ni[k]));
      }
      wkey = wave_max_key(lk2, lane);
    }
  }
}

// ---------------- gather sampled points (pp copied — bit-identical) ----------------
__global__ void k_gather(const float4* __restrict__ Pin, const int* __restrict__ idx,
                         float4* __restrict__ Pout, int n, int m, int total) {
  int t = blockIdx.x * blockDim.x + threadIdx.x;
  if (t >= total) return;
  int b = t / m;
  Pout[t] = Pin[(size_t)b * n + idx[t]];
}

// ---------------- KNN: one wave per query; exact expanded-form d2 ----------------
__global__ __launch_bounds__(256) void k_knn(
    const float4* __restrict__ Pq, const float4* __restrict__ Pc,
    int n, int m, int* __restrict__ knn) {
  int gw = (blockIdx.x * 256 + threadIdx.x) >> 6;
  int lane = threadIdx.x & 63;
  int b = gw / m;
  float4 q = Pq[gw];
  const float4* C = Pc + (size_t)b * n;
  float ad[8];
  int ai[8];
#pragma unroll
  for (int s = 0; s < 8; ++s) { ad[s] = FLT_MAX; ai[s] = 0x7fffffff; }
  for (int j = lane; j < n; j += 64) {
    float4 c = C[j];
    float dot = __fadd_rn(__fadd_rn(__fmul_rn(q.x, c.x), __fmul_rn(q.y, c.y)), __fmul_rn(q.z, c.z));
    float d2 = __fsub_rn(__fadd_rn(q.w, c.w), __fmul_rn(2.f, dot));  // (qq+pp) - 2*dot
    if (d2 < ad[7] || (d2 == ad[7] && j < ai[7])) {
      float cd = d2; int ci = j;
#pragma unroll
      for (int s = 0; s < 8; ++s) {
        bool sw = (cd < ad[s]) || (cd == ad[s] && ci < ai[s]);
        float td = ad[s]; int ti = ai[s];
        ad[s] = sw ? cd : td; ai[s] = sw ? ci : ti;
        cd = sw ? td : cd;  ci = sw ? ti : ci;
      }
    }
  }
  int pos = 0;
  int* kout = knn + (size_t)gw * 8;
#pragma unroll
  for (int r = 0; r < 8; ++r) {
    float hv = FLT_MAX; int hi = 0x7fffffff;
#pragma unroll
    for (int s = 7; s >= 0; --s)
      if (pos == s) { hv = ad[s]; hi = ai[s]; }
    float v = hv; int ix = hi;
#pragma unroll
    for (int off = 1; off < 64; off <<= 1) {
      float ov = __shfl_xor(v, off);
      int oi = __shfl_xor(ix, off);
      if (ov < v || (ov == v && oi < ix)) { v = ov; ix = oi; }
    }
    if (hv == v && hi == ix) pos++;  // unique owner (point indices unique)
    if (lane == 0) kout[r] = ix;
  }
}

// ---------------- grouped feature transform + BN/ReLU + maxpool over k=8 ----------------
template <int CINF, int COUT>
__global__ __launch_bounds__(COUT) void k_feat(
    const float4* __restrict__ Pq, const float4* __restrict__ Pc,
    const float* __restrict__ Xin, const int* __restrict__ knn,
    const float* __restrict__ W, const float* __restrict__ g, const float* __restrict__ bt,
    float* __restrict__ Xout, int n, int m) {
  constexpr int F = 3 + CINF;
  __shared__ float sf[8][F];
  int bi = blockIdx.x;  // = b*m + i
  int b = bi / m;
  int tid = threadIdx.x;
  float4 q = Pq[bi];
  const int* kn = knn + (size_t)bi * 8;
  if (tid < 8) {
    int nb = kn[tid];
    float4 c = Pc[(size_t)b * n + nb];
    sf[tid][0] = c.x - q.x;
    sf[tid][1] = c.y - q.y;
    sf[tid][2] = c.z - q.z;
  }
  for (int e = tid; e < 8 * CINF; e += COUT) {
    int k = e / CINF, j = e - k * CINF;
    int nb = kn[k];
    sf[k][3 + j] = Xin[((size_t)b * n + nb) * CINF + j];
  }
  __syncthreads();
  int c = tid;
  float acc[8] = {0.f, 0.f, 0.f, 0.f, 0.f, 0.f, 0.f, 0.f};
  for (int j = 0; j < F; ++j) {
    float w = W[(size_t)j * COUT + c];
#pragma unroll
    for (int k = 0; k < 8; ++k) acc[k] = fmaf(sf[k][j], w, acc[k]);
  }
  float sc = g[c] * BNI, bb = bt[c];
  float mx = 0.f;
#pragma unroll
  for (int k = 0; k < 8; ++k) mx = fmaxf(mx, fmaf(acc[k], sc, bb));
  Xout[(size_t)bi * COUT + c] = mx;
}

// ---------------- head: mean-pool + fc/bn/relu + fc ----------------
__global__ __launch_bounds__(512) void k_head(
    const float* __restrict__ X5, const float* __restrict__ Wc1, const float* __restrict__ bc1,
    const float* __restrict__ gc, const float* __restrict__ bcl,
    const float* __restrict__ Wc2, const float* __restrict__ bc2,
    float* __restrict__ out, int m5) {
  __shared__ float sp[512];
  __shared__ float sh[256];
  int b = blockIdx.x, tid = threadIdx.x;
  float s = 0.f;
  for (int i = 0; i < m5; ++i) s += X5[((size_t)b * m5 + i) * 512 + tid];
  sp[tid] = s * (1.0f / m5);
  __syncthreads();
  if (tid < 256) {
    float a = bc1[tid];
    for (int j = 0; j < 512; ++j) a = fmaf(sp[j], Wc1[j * 256 + tid], a);
    a = a * (gc[tid] * BNI) + bcl[tid];
    sh[tid] = fmaxf(a, 0.f);
  }
  __syncthreads();
  if (tid < 40) {
    float a = bc2[tid];
    for (int j = 0; j < 256; ++j) a = fmaf(sh[j], Wc2[j * 40 + tid], a);
    out[b * 40 + tid] = a;
  }
}

extern "C" void kernel_launch(void* const* d_in, const int* in_sizes, int n_in,
                              void* d_out, int out_size, void* d_ws, size_t ws_size,
                              hipStream_t stream) {
  const float* p0 = (const float*)d_in[0];
  const float* x0 = (const float*)d_in[1];
  const int B = in_sizes[2];
  const int N = in_sizes[0] / 3;
  const int n = N / B;  // 8192
  const float* W1 = (const float*)d_in[3];
  const float* g1 = (const float*)d_in[4];
  const float* b1 = (const float*)d_in[5];
  const float* W2 = (const float*)d_in[6];
  const float* g2 = (const float*)d_in[7];
  const float* b2 = (const float*)d_in[8];
  const float* W3 = (const float*)d_in[9];
  const float* g3 = (const float*)d_in[10];
  const float* b3 = (const float*)d_in[11];
  const float* W4 = (const float*)d_in[12];
  const float* g4 = (const float*)d_in[13];
  const float* b4 = (const float*)d_in[14];
  const float* W5 = (const float*)d_in[15];
  const float* g5 = (const float*)d_in[16];
  const float* b5 = (const float*)d_in[17];
  const float* Wc1 = (const float*)d_in[18];
  const float* bc1 = (const float*)d_in[19];
  const float* gcls = (const float*)d_in[20];
  const float* bcls = (const float*)d_in[21];
  const float* Wc2 = (const float*)d_in[22];
  const float* bc2 = (const float*)d_in[23];
  float* out = (float*)d_out;

  const int m2 = n / 4, m3 = m2 / 4, m4 = m3 / 4, m5 = m4 / 4;

  char* ws = (char*)d_ws;
  size_t off = 0;
  auto alloc = [&](size_t bytes) -> void* {
    void* p = ws + off;
    off += (bytes + 255) & ~(size_t)255;
    return p;
  };
  float4* P2 = (float4*)alloc((size_t)N * 16);
  float* X1 = (float*)alloc((size_t)N * 32 * 4);
  float4* P3 = (float4*)alloc((size_t)B * m2 * 16);
  float4* P4s = (float4*)alloc((size_t)B * m3 * 16);
  float4* P5 = (float4*)alloc((size_t)B * m4 * 16);
  float4* P6 = (float4*)alloc((size_t)B * m5 * 16);
  int* fpsI = (int*)alloc((size_t)B * m2 * 4);
  int* knnI = (int*)alloc((size_t)B * m2 * 8 * 4);
  float* X2 = (float*)alloc((size_t)B * m2 * 64 * 4);
  float* X3 = (float*)alloc((size_t)B * m3 * 128 * 4);
  float* X4 = (float*)alloc((size_t)B * m4 * 256 * 4);
  float* X5 = (float*)alloc((size_t)B * m5 * 512 * 4);
  float4* Psort = (float4*)alloc((size_t)N * 16);
  float* bbox = (float*)alloc((size_t)B * 8 * 4);
  int* hist = (int*)alloc((size_t)B * 512 * 4);
  int* cursor = (int*)alloc((size_t)B * 512 * 4);

  auto sort_stage = [&](const float4* P, int ns) {
    int total = B * ns;
    hipMemsetAsync(hist, 0, (size_t)B * 512 * 4, stream);
    k_bbox<<<B, 256, 0, stream>>>(P, ns, bbox);
    k_hist<<<(total + 255) / 256, 256, 0, stream>>>(P, bbox, hist, ns, total);
    k_scan<<<B, 512, 0, stream>>>(hist, cursor);
    k_scatter<<<(total + 255) / 256, 256, 0, stream>>>(P, bbox, cursor, Psort, ns, total);
  };

  k_prep<<<(N + 255) / 256, 256, 0, stream>>>(p0, P2, N);
  k_enc1<<<(N * 32 + 255) / 256, 256, 0, stream>>>(p0, x0, W1, g1, b1, X1, N);

  // stage 2: n=8192 -> m=2048, feat 3+32 -> 64
  sort_stage(P2, n);
  k_fps<8, 16><<<B, 1024, 0, stream>>>(Psort, P2, n, m2, fpsI);
  k_gather<<<(B * m2 + 255) / 256, 256, 0, stream>>>(P2, fpsI, P3, n, m2, B * m2);
  k_knn<<<(B * m2) / 4, 256, 0, stream>>>(P3, P2, n, m2, knnI);
  k_feat<32, 64><<<B * m2, 64, 0, stream>>>(P3, P2, X1, knnI, W2, g2, b2, X2, n, m2);

  // stage 3: 2048 -> 512, 3+64 -> 128
  sort_stage(P3, m2);
  k_fps<4, 8><<<B, 512, 0, stream>>>(Psort, P3, m2, m3, fpsI);
  k_gather<<<(B * m3 + 255) / 256, 256, 0, stream>>>(P3, fpsI, P4s, m2, m3, B * m3);
  k_knn<<<(B * m3) / 4, 256, 0, stream>>>(P4s, P3, m2, m3, knnI);
  k_feat<64, 128><<<B * m3, 128, 0, stream>>>(P4s, P3, X2, knnI, W3, g3, b3, X3, m2, m3);

  // stage 4: 512 -> 128, 3+128 -> 256
  sort_stage(P4s, m3);
  k_fps<2, 4><<<B, 256, 0, stream>>>(Psort, P4s, m3, m4, fpsI);
  k_gather<<<(B * m4 + 255) / 256, 256, 0, stream>>>(P4s, fpsI, P5, m3, m4, B * m4);
  k_knn<<<(B * m4) / 4, 256, 0, stream>>>(P5, P4s, m3, m4, knnI);
  k_feat<128, 256><<<B * m4, 256, 0, stream>>>(P5, P4s, X3, knnI, W4, g4, b4, X4, m3, m4);

  // stage 5: 128 -> 32, 3+256 -> 512
  sort_stage(P5, m4);
  k_fps<1, 2><<<B, 128, 0, stream>>>(Psort, P5, m4, m5, fpsI);
  k_gather<<<(B * m5 + 255) / 256, 256, 0, stream>>>(P5, fpsI, P6, m4, m5, B * m5);
  k_knn<<<(B * m5) / 4, 256, 0, stream>>>(P6, P5, m4, m5, knnI);
  k_feat<256, 512><<<B * m5, 512, 0, stream>>>(P6, P5, X4, knnI, W5, g5, b5, X5, m4, m5);

  // head
  k_head<<<B, 512, 0, stream>>>(X5, Wc1, bc1, gcls, bcls, Wc2, bc2, out, m5);
}